// Round 12
// baseline (501.314 us; speedup 1.0000x reference)
//
#include <hip/hip_runtime.h>

#define NN 100000
#define NE 1600000
#define NLAYERS 5
#define BN_EPSF 1e-5f
#define NB 391                 // ceil(NN/256) buckets of 256 nodes
#define CAPR 4608              // raw edges capacity per bucket
#define SRCCAP 2250000         // padded srcList ints (+ slack)
#define NOCT 12500             // NN / 8 exactly
#define LBLK 768               // gather blocks (3/CU at 48KB LDS)
#define TOTW (LBLK * 4)        // 3072 waves

typedef unsigned short bfu;
typedef unsigned short u16x4 __attribute__((ext_vector_type(4)));
typedef unsigned short u16x8 __attribute__((ext_vector_type(8)));
typedef float f32x4v __attribute__((ext_vector_type(4)));

__device__ inline float bf2f(bfu u) {
    unsigned x = ((unsigned)u) << 16;
    return __builtin_bit_cast(float, x);
}
__device__ inline bfu f2bf(float f) {
    unsigned x = __builtin_bit_cast(unsigned, f);
    unsigned r = (x + 0x7FFF + ((x >> 16) & 1)) >> 16;
    return (bfu)r;
}
__device__ inline f32x4v cvt4(u16x4 v) {
    f32x4v r;
    r.x = bf2f(v.x); r.y = bf2f(v.y); r.z = bf2f(v.z); r.w = bf2f(v.w);
    return r;
}
__device__ inline void acc8(uint4 d, f32x4v& aL, f32x4v& aH) {
    aL.x += __builtin_bit_cast(float, d.x << 16);
    aL.y += __builtin_bit_cast(float, d.x & 0xFFFF0000u);
    aL.z += __builtin_bit_cast(float, d.y << 16);
    aL.w += __builtin_bit_cast(float, d.y & 0xFFFF0000u);
    aH.x += __builtin_bit_cast(float, d.z << 16);
    aH.y += __builtin_bit_cast(float, d.z & 0xFFFF0000u);
    aH.z += __builtin_bit_cast(float, d.w << 16);
    aH.w += __builtin_bit_cast(float, d.w & 0xFFFF0000u);
}

#define GLL16(gp, lp) __builtin_amdgcn_global_load_lds( \
    (const __attribute__((address_space(1))) void*)(gp), \
    (__attribute__((address_space(3))) void*)(lp), 16, 0, 0)
#define GLL4(gp, lp) __builtin_amdgcn_global_load_lds( \
    (const __attribute__((address_space(1))) void*)(gp), \
    (__attribute__((address_space(3))) void*)(lp), 4, 0, 0)
#define WAITV0 do { asm volatile("s_waitcnt vmcnt(0)" ::: "memory"); \
                    __builtin_amdgcn_sched_barrier(0); } while (0)

// ---------------- embed -> bf16 h0 (+zero dummy); block0 also inits bcnt+identity sums ----------------
__global__ __launch_bounds__(256) void k_embed(const int* __restrict__ x,
                                               const float* __restrict__ table,
                                               bfu* __restrict__ P,
                                               int* __restrict__ bcnt,
                                               float* __restrict__ sums) {
    int t = threadIdx.x;
    if (blockIdx.x == 0) {
        for (int k = t; k < NB; k += 256) bcnt[k] = 0;
        if (t < 64) sums[t] = 0.f;                                  // mean = 0
        else if (t < 128) sums[t] = (float)NN * (1.0f - BN_EPSF);   // var = 1-eps -> inv = 1
    }
    int idx = blockIdx.x * 256 + t;
    if (idx >= (NN + 1) * 16) return;
    int i = idx >> 4, fq = idx & 15;
    u16x4 o = {0, 0, 0, 0};
    if (i < NN) {
        f32x4v v = *(const f32x4v*)(table + x[2 * i] * 64 + fq * 4);
        o.x = f2bf(v.x); o.y = f2bf(v.y); o.z = f2bf(v.z); o.w = f2bf(v.w);
    }
    *(u16x4*)(P + (size_t)i * 64 + fq * 4) = o;
}

// ---------------- partition edges into fixed-capacity bucket windows ----------------
__global__ __launch_bounds__(256) void k_part(const int* __restrict__ src,
                                              const int* __restrict__ dst,
                                              int* __restrict__ bcnt,
                                              int* __restrict__ tmp) {
    __shared__ int h[NB];
    __shared__ int hb[NB];
    int t = threadIdx.x;
    for (int k = t; k < NB; k += 256) h[k] = 0;
    __syncthreads();
    int base = blockIdx.x * 2048;
    int v_[8], b_[8], r_[8];
#pragma unroll
    for (int u = 0; u < 8; ++u) {
        int e = base + u * 256 + t;
        if (e < NE) {
            int d = dst[e];
            b_[u] = d >> 8;
            v_[u] = src[e] | ((d & 255) << 20);
            r_[u] = atomicAdd(&h[b_[u]], 1);
        } else {
            b_[u] = -1;
        }
    }
    __syncthreads();
    for (int k = t; k < NB; k += 256)
        hb[k] = h[k] ? (k * CAPR + atomicAdd(&bcnt[k], h[k])) : 0;
    __syncthreads();
#pragma unroll
    for (int u = 0; u < 8; ++u) {
        if (b_[u] >= 0) tmp[hb[b_[u]] + r_[u]] = v_[u];
    }
}

// ---------------- per-bucket: degree count + chunk-class histogram ----------------
__global__ __launch_bounds__(256) void k_cnt(const int* __restrict__ tmp,
                                             const int* __restrict__ bcnt,
                                             int* __restrict__ pk,
                                             int* __restrict__ gbh) {
    __shared__ int cnt[256];
    __shared__ int lbh[64];
    int b = blockIdx.x, t = threadIdx.x;
    int n = bcnt[b];
    const int* w = tmp + (size_t)b * CAPR;
    cnt[t] = 0;
    if (t < 64) lbh[t] = 0;
    __syncthreads();
    for (int k = t; k < n; k += 256) atomicAdd(&cnt[w[k] >> 20], 1);
    __syncthreads();
    int node = b * 256 + t;
    int c = cnt[t];
    int pkv = 0;
    if (node < NN) {
        int m = c ? ((c + 7) >> 3) : 1;      // chunks of 8 edges
        int rl = atomicAdd(&lbh[m], 1);
        pkv = c | (rl << 9) | (m << 17);
    }
    pk[b * 256 + t] = pkv;
    __syncthreads();
    if (t < 64) gbh[b * 64 + t] = lbh[t];
}

// ---------------- global scan: per-class bucket prefixes + class tables ----------------
__global__ void k_scan(const int* __restrict__ gbh, int* __restrict__ gBinBase,
                       int* __restrict__ tabs) {
    __shared__ int tot[64];
    int t = threadIdx.x;
    int run = 0;
    for (int b = 0; b < NB; ++b) {
        int v = gbh[b * 64 + t];
        gBinBase[b * 64 + t] = run;
        run += v;
    }
    tot[t] = run;
    __syncthreads();
    if (t == 0) {
        int nb = 0;
        long cb = 0;
        for (int m = 63; m >= 1; --m) {
            int cN = tot[m];
            if (!cN) continue;
            tabs[200 + m] = nb;
            tabs[264 + m] = (int)cb;
            nb += cN;
            cb += (long)cN * m;
        }
    }
}

// ---------------- place: sorted work list + 8-padded srcList ----------------
__global__ __launch_bounds__(256) void k_place(const int* __restrict__ tmp,
                                               const int* __restrict__ bcnt,
                                               const int* __restrict__ pk,
                                               const int* __restrict__ gBinBase,
                                               const int* __restrict__ tabs,
                                               int2* __restrict__ work,
                                               int* __restrict__ srcList) {
    __shared__ int cur[256];
    int b = blockIdx.x, t = threadIdx.x;
    int n = bcnt[b];
    const int* w = tmp + (size_t)b * CAPR;
    int node = b * 256 + t;
    int pkv = pk[b * 256 + t];
    if (node < NN) {
        int c = pkv & 511;
        int rl = (pkv >> 9) & 255;
        int m = pkv >> 17;
        int rank = gBinBase[b * 64 + m] + rl;
        int sp = tabs[200 + m] + rank;
        int beg = (tabs[264 + m] + rank * m) * 8;
        work[sp] = make_int2(beg, node | (m << 20));
        cur[t] = beg;
        for (int k = c; k < m * 8; ++k) srcList[beg + k] = NN;   // dummy row
    }
    __syncthreads();
    for (int k = t; k < n; k += 256) {
        int v = w[k];
        int pos = atomicAdd(&cur[v >> 20], 1);
        srcList[pos] = v & 0xFFFFF;
    }
}

// ---------------- gather: octet/wave, folded BN affine, fused stats ----------------
__global__ __launch_bounds__(256) void k_gather(
    const bfu* __restrict__ Pin, bfu* __restrict__ Pout, float* __restrict__ Q,
    const int2* __restrict__ work, const int* __restrict__ srcList,
    float* __restrict__ partial, const float* __restrict__ sums, int last) {
    __shared__ uint4 rows[4][8][64];
    __shared__ int idxb[4][2][8][64];
    __shared__ float bsum[64], bsq[64];
    int t = threadIdx.x;
    int ws = t >> 6, l = t & 63;
    int g = l >> 3, sl = l & 7;
    if (t < 64) { bsum[t] = 0.f; bsq[t] = 0.f; }
    __syncthreads();

    // per-lane affine params for features sl*8 .. sl*8+7
    f32x4v invA, invB, mqA, mqB;
#pragma unroll
    for (int j = 0; j < 8; ++j) {
        float s = sums[sl * 8 + j], q2 = sums[64 + sl * 8 + j];
        float mean = s / (float)NN;
        float var = fmaxf(q2 / (float)NN - mean * mean, 0.f);
        float iv = rsqrtf(var + BN_EPSF);
        float mv = bf2f(f2bf(mean));     // must match the dummy row exactly
        if (j < 4) { invA[j] = iv; mqA[j] = mv; }
        else { invB[j - 4] = iv; mqB[j - 4] = mv; }
    }

    int oct = blockIdx.x * 4 + ws;
    f32x4v lsumL = {0.f, 0.f, 0.f, 0.f}, lsumH = {0.f, 0.f, 0.f, 0.f};
    f32x4v lsqL = {0.f, 0.f, 0.f, 0.f}, lsqH = {0.f, 0.f, 0.f, 0.f};

    int2 wcur = make_int2(0, 0);
    if (l < 8) wcur = work[(size_t)oct * 8 + l];
    int bg = __shfl(wcur.x, g);
    int wy = __shfl(wcur.y, g);
    int node = wy & 0xFFFFF;
    int mg = wy >> 20;
    int mr = (l < 8) ? (wcur.y >> 20) : 0;
    mr = max(mr, __shfl_xor(mr, 1));
    mr = max(mr, __shfl_xor(mr, 2));
    mr = max(mr, __shfl_xor(mr, 4));
    int mMax = __shfl(mr, 0);
    int par = 0;
    if (mMax <= 8) {
        for (int w = 0; w < mMax; ++w)
            GLL4(srcList + bg + w * 8 + sl, &idxb[ws][0][w][0]);
    }
    WAITV0;

    for (;;) {
        int nxt = oct + TOTW;
        f32x4v aL = {0.f, 0.f, 0.f, 0.f}, aH = {0.f, 0.f, 0.f, 0.f};
        int bgN = 0, nodeN = 0, mgN = 0, mMaxN = 0;
        float cDp;
        uint4 selfr = *(const uint4*)(Pin + (size_t)node * 64 + sl * 8);
        if (mMax <= 8) {
            cDp = 8.f * (float)mMax + 0.5f;
            for (int w = 0; w < mMax; ++w) {
                bool lastw = (w == mMax - 1);
                int2 wnx = make_int2(0, 0);
                if (lastw && l < 8 && nxt < NOCT) wnx = work[(size_t)nxt * 8 + l];
                int sj[8];
#pragma unroll
                for (int j = 0; j < 8; ++j) sj[j] = idxb[ws][par][w][g * 8 + j];
#pragma unroll
                for (int j = 0; j < 8; ++j) {
                    int e = w * 8 + j;
                    int idv = (e < (mg << 3)) ? sj[j] : NN;
                    GLL16(Pin + (size_t)idv * 64 + sl * 8, &rows[ws][j][0]);
                }
                if (lastw) {
                    bgN = __shfl(wnx.x, g);
                    int wyN = __shfl(wnx.y, g);
                    nodeN = wyN & 0xFFFFF;
                    mgN = wyN >> 20;
                    int mrN = (l < 8) ? (wnx.y >> 20) : 0;
                    mrN = max(mrN, __shfl_xor(mrN, 1));
                    mrN = max(mrN, __shfl_xor(mrN, 2));
                    mrN = max(mrN, __shfl_xor(mrN, 4));
                    mMaxN = __shfl(mrN, 0);
                    if (nxt < NOCT && mMaxN <= 8) {
                        for (int w2 = 0; w2 < mMaxN; ++w2)
                            GLL4(srcList + bgN + w2 * 8 + sl, &idxb[ws][par ^ 1][w2][0]);
                    }
                }
                WAITV0;
#pragma unroll
                for (int j = 0; j < 8; ++j) acc8(rows[ws][j][l], aL, aH);
            }
        } else {
            // rare fallback: octet containing deg > 64 node
            cDp = 8.f * (float)mg + 0.5f;
            int2 wnx = make_int2(0, 0);
            if (l < 8 && nxt < NOCT) wnx = work[(size_t)nxt * 8 + l];
            bgN = __shfl(wnx.x, g);
            int wyN = __shfl(wnx.y, g);
            nodeN = wyN & 0xFFFFF;
            mgN = wyN >> 20;
            int mrN = (l < 8) ? (wnx.y >> 20) : 0;
            mrN = max(mrN, __shfl_xor(mrN, 1));
            mrN = max(mrN, __shfl_xor(mrN, 2));
            mrN = max(mrN, __shfl_xor(mrN, 4));
            mMaxN = __shfl(mrN, 0);
            if (nxt < NOCT && mMaxN <= 8) {
                for (int w2 = 0; w2 < mMaxN; ++w2)
                    GLL4(srcList + bgN + w2 * 8 + sl, &idxb[ws][par ^ 1][w2][0]);
            }
            WAITV0;
            for (int e = 0; e < (mg << 3); ++e) {
                int idv = srcList[bg + e];
                acc8(*(const uint4*)(Pin + (size_t)idv * 64 + sl * 8), aL, aH);
            }
        }
        // fold self + affine: a = inv*(Sum + 0.5*P[i] - cDp*mq)
        {
            f32x4v z = {0.f, 0.f, 0.f, 0.f};
            f32x4v sLo = z, sHi = z;
            acc8(selfr, sLo, sHi);
            aL = (aL + sLo * 0.5f - mqA * cDp) * invA;
            aH = (aH + sHi * 0.5f - mqB * cDp) * invB;
        }
        if (last) {
            float* qr = Q + (size_t)node * 64 + sl * 8;
            *(f32x4v*)qr = aL;
            *(f32x4v*)(qr + 4) = aH;
        } else {
            u16x8 o;
#pragma unroll
            for (int j = 0; j < 4; ++j) { o[j] = f2bf(aL[j]); o[4 + j] = f2bf(aH[j]); }
            *(u16x8*)(Pout + (size_t)node * 64 + sl * 8) = o;
        }
        lsumL += aL; lsumH += aH;
        lsqL += aL * aL; lsqH += aH * aH;
        if (nxt >= NOCT) break;
        oct = nxt; bg = bgN; node = nodeN; mg = mgN; mMax = mMaxN; par ^= 1;
    }

#pragma unroll
    for (int mask = 8; mask <= 32; mask <<= 1) {
#pragma unroll
        for (int j = 0; j < 4; ++j) {
            lsumL[j] += __shfl_xor(lsumL[j], mask);
            lsumH[j] += __shfl_xor(lsumH[j], mask);
            lsqL[j] += __shfl_xor(lsqL[j], mask);
            lsqH[j] += __shfl_xor(lsqH[j], mask);
        }
    }
    if (g == 0) {
#pragma unroll
        for (int j = 0; j < 4; ++j) {
            atomicAdd(&bsum[sl * 8 + j], lsumL[j]);
            atomicAdd(&bsum[sl * 8 + 4 + j], lsumH[j]);
            atomicAdd(&bsq[sl * 8 + j], lsqL[j]);
            atomicAdd(&bsq[sl * 8 + 4 + j], lsqH[j]);
        }
    }
    __syncthreads();
    if (t < 64) {
        partial[(size_t)blockIdx.x * 128 + t] = bsum[t];
        partial[(size_t)blockIdx.x * 128 + 64 + t] = bsq[t];
    }
}

// ---------------- reduce partials -> sums; write bf16(mean) dummy row ----------------
__global__ void k_red(const float* __restrict__ partial, float* __restrict__ sums,
                      bfu* __restrict__ Pdummy) {
    __shared__ float acc[512];
    int t = threadIdx.x;                 // 512
    int col = t & 127, part = t >> 7;    // 4 row-chunks
    float s = 0.f;
    for (int b = part; b < LBLK; b += 4) s += partial[(size_t)b * 128 + col];
    acc[t] = s;
    __syncthreads();
    if (t < 128) {
        float r = acc[t] + acc[t + 128] + acc[t + 256] + acc[t + 384];
        sums[t] = r;
        acc[t] = r;
    }
    __syncthreads();
    if (t < 64) Pdummy[t] = f2bf(acc[t] / (float)NN);
}

// ---------------- final: normalize agg(Q) -> fp32 out ----------------
__global__ __launch_bounds__(256) void k_final(const float* __restrict__ Q,
                                               const float* __restrict__ sums,
                                               float* __restrict__ out) {
    __shared__ float prm[128];
    int t = threadIdx.x;
    if (t < 64) {
        float s = sums[t], q2 = sums[64 + t];
        float mean = s / (float)NN;
        float var = fmaxf(q2 / (float)NN - mean * mean, 0.f);
        prm[t] = rsqrtf(var + BN_EPSF);
        prm[64 + t] = mean;
    }
    __syncthreads();
    int idx = blockIdx.x * 256 + t;
    if (idx >= NN * 16) return;
    int i = idx >> 4, fq = idx & 15;
    f32x4v a = *(const f32x4v*)(Q + (size_t)i * 64 + fq * 4);
    f32x4v o;
    o.x = (a.x - prm[64 + fq * 4 + 0]) * prm[fq * 4 + 0];
    o.y = (a.y - prm[64 + fq * 4 + 1]) * prm[fq * 4 + 1];
    o.z = (a.z - prm[64 + fq * 4 + 2]) * prm[fq * 4 + 2];
    o.w = (a.w - prm[64 + fq * 4 + 3]) * prm[fq * 4 + 3];
    *(f32x4v*)(out + (size_t)i * 64 + fq * 4) = o;
}

extern "C" void kernel_launch(void* const* d_in, const int* in_sizes, int n_in,
                              void* d_out, int out_size, void* d_ws, size_t ws_size,
                              hipStream_t stream) {
    const int* x = (const int*)d_in[0];
    const int* ei = (const int*)d_in[1];
    const float* table = (const float*)d_in[2];
    const int* src = ei;
    const int* dst = ei + NE;
    float* out = (float*)d_out;

    // workspace carve-up (~70 MB)
    bfu* PA = (bfu*)d_ws;                                  // (NN+1)*64 bf16
    bfu* PB = PA + (size_t)(NN + 1) * 64;                  // (NN+1)*64 bf16
    float* Q = (float*)(PB + (size_t)(NN + 1) * 64);       // NN*64 f32
    int* srcList = (int*)(Q + (size_t)NN * 64);            // SRCCAP
    int* tmp = srcList + SRCCAP;                           // NB*CAPR
    int2* work = (int2*)(tmp + (size_t)NB * CAPR);         // NN int2
    int* pk = (int*)(work + NN);                           // NB*256
    int* gBinBase = pk + NB * 256;                         // NB*64
    int* gbh = gBinBase + NB * 64;                         // NB*64
    int* bcnt = gbh + NB * 64;                             // NB
    float* partial = (float*)(bcnt + NB);                  // LBLK*128
    float* sums = partial + (size_t)LBLK * 128;            // 128
    int* tabs = (int*)(sums + 128);                        // 512

    k_embed<<<((NN + 1) * 16 + 255) / 256, 256, 0, stream>>>(x, table, PA, bcnt, sums);

    const int NPB = (NE + 2047) / 2048;  // 782
    k_part<<<NPB, 256, 0, stream>>>(src, dst, bcnt, tmp);
    k_cnt<<<NB, 256, 0, stream>>>(tmp, bcnt, pk, gbh);
    k_scan<<<1, 64, 0, stream>>>(gbh, gBinBase, tabs);
    k_place<<<NB, 256, 0, stream>>>(tmp, bcnt, pk, gBinBase, tabs, work, srcList);

    // 5 layers: gather (folded BN affine + stats) -> reduce (params + dummy-mean row)
    bfu* Pin = PA;
    bfu* Pout = PB;
    for (int L = 0; L < NLAYERS; ++L) {
        int last = (L == NLAYERS - 1);
        k_gather<<<LBLK, 256, 0, stream>>>(Pin, Pout, Q, work, srcList, partial, sums, last);
        k_red<<<1, 512, 0, stream>>>(partial, sums, Pout + (size_t)NN * 64);
        bfu* tswap = Pin; Pin = Pout; Pout = tswap;
    }
    k_final<<<(NN * 16 + 255) / 256, 256, 0, stream>>>(Q, sums, out);
}

// Round 13
// 257.388 us; speedup vs baseline: 1.9477x; 1.9477x over previous
//
#include <hip/hip_runtime.h>

#define NN 100000
#define NE 1600000
#define NLAYERS 5
#define BN_EPSF 1e-5f
#define NB 391                 // ceil(NN/256) buckets of 256 nodes
#define CAPR 4608              // raw edges capacity per bucket
#define SRCCAP 2250000         // padded srcList ints (+ slack)
#define NOCT 12500             // NN / 8 exactly
#define LBLK 768               // gather blocks (3/CU at 48KB LDS)
#define TOTW (LBLK * 4)        // 3072 waves

typedef unsigned short bfu;
typedef unsigned short u16x4 __attribute__((ext_vector_type(4)));
typedef unsigned short u16x8 __attribute__((ext_vector_type(8)));
typedef float f32x4v __attribute__((ext_vector_type(4)));

__device__ inline float bf2f(bfu u) {
    unsigned x = ((unsigned)u) << 16;
    return __builtin_bit_cast(float, x);
}
__device__ inline bfu f2bf(float f) {
    unsigned x = __builtin_bit_cast(unsigned, f);
    unsigned r = (x + 0x7FFF + ((x >> 16) & 1)) >> 16;
    return (bfu)r;
}
__device__ inline f32x4v cvt4(u16x4 v) {
    f32x4v r;
    r.x = bf2f(v.x); r.y = bf2f(v.y); r.z = bf2f(v.z); r.w = bf2f(v.w);
    return r;
}
__device__ inline void acc8(uint4 d, f32x4v& aL, f32x4v& aH) {
    aL.x += __builtin_bit_cast(float, d.x << 16);
    aL.y += __builtin_bit_cast(float, d.x & 0xFFFF0000u);
    aL.z += __builtin_bit_cast(float, d.y << 16);
    aL.w += __builtin_bit_cast(float, d.y & 0xFFFF0000u);
    aH.x += __builtin_bit_cast(float, d.z << 16);
    aH.y += __builtin_bit_cast(float, d.z & 0xFFFF0000u);
    aH.z += __builtin_bit_cast(float, d.w << 16);
    aH.w += __builtin_bit_cast(float, d.w & 0xFFFF0000u);
}

#define GLL16(gp, lp) __builtin_amdgcn_global_load_lds( \
    (const __attribute__((address_space(1))) void*)(gp), \
    (__attribute__((address_space(3))) void*)(lp), 16, 0, 0)
#define GLL4(gp, lp) __builtin_amdgcn_global_load_lds( \
    (const __attribute__((address_space(1))) void*)(gp), \
    (__attribute__((address_space(3))) void*)(lp), 4, 0, 0)
#define WAITV0 do { asm volatile("s_waitcnt vmcnt(0)" ::: "memory"); \
                    __builtin_amdgcn_sched_barrier(0); } while (0)

// ---------------- embed -> bf16 h0 (+zero dummy rows in BOTH P buffers); block0 inits bcnt+partial2 ----------------
__global__ __launch_bounds__(256) void k_embed(const int* __restrict__ x,
                                               const float* __restrict__ table,
                                               bfu* __restrict__ PA,
                                               bfu* __restrict__ PB,
                                               int* __restrict__ bcnt,
                                               float* __restrict__ partial2) {
    int t = threadIdx.x;
    if (blockIdx.x == 0) {
        for (int k = t; k < NB; k += 256) bcnt[k] = 0;
        // identity stats: mean=0, var=1-eps -> inv=1
        if (t < 128) {
            partial2[t] = (t >= 64) ? (float)NN * (1.0f - BN_EPSF) : 0.f;
            for (int r = 1; r < 8; ++r) partial2[r * 128 + t] = 0.f;
        }
    }
    int idx = blockIdx.x * 256 + t;
    if (idx >= (NN + 1) * 16) return;
    int i = idx >> 4, fq = idx & 15;
    u16x4 o = {0, 0, 0, 0};
    if (i < NN) {
        f32x4v v = *(const f32x4v*)(table + x[2 * i] * 64 + fq * 4);
        o.x = f2bf(v.x); o.y = f2bf(v.y); o.z = f2bf(v.z); o.w = f2bf(v.w);
    } else {
        *(u16x4*)(PB + (size_t)i * 64 + fq * 4) = o;   // PB dummy row = 0
    }
    *(u16x4*)(PA + (size_t)i * 64 + fq * 4) = o;
}

// ---------------- partition edges into fixed-capacity bucket windows ----------------
__global__ __launch_bounds__(256) void k_part(const int* __restrict__ src,
                                              const int* __restrict__ dst,
                                              int* __restrict__ bcnt,
                                              int* __restrict__ tmp) {
    __shared__ int h[NB];
    __shared__ int hb[NB];
    int t = threadIdx.x;
    for (int k = t; k < NB; k += 256) h[k] = 0;
    __syncthreads();
    int base = blockIdx.x * 2048;
    int v_[8], b_[8], r_[8];
#pragma unroll
    for (int u = 0; u < 8; ++u) {
        int e = base + u * 256 + t;
        if (e < NE) {
            int d = dst[e];
            b_[u] = d >> 8;
            v_[u] = src[e] | ((d & 255) << 20);
            r_[u] = atomicAdd(&h[b_[u]], 1);
        } else {
            b_[u] = -1;
        }
    }
    __syncthreads();
    for (int k = t; k < NB; k += 256)
        hb[k] = h[k] ? (k * CAPR + atomicAdd(&bcnt[k], h[k])) : 0;
    __syncthreads();
#pragma unroll
    for (int u = 0; u < 8; ++u) {
        if (b_[u] >= 0) tmp[hb[b_[u]] + r_[u]] = v_[u];
    }
}

// ---------------- per-bucket: degree count + chunk-class histogram ----------------
__global__ __launch_bounds__(256) void k_cnt(const int* __restrict__ tmp,
                                             const int* __restrict__ bcnt,
                                             int* __restrict__ pk,
                                             int* __restrict__ gbh) {
    __shared__ int cnt[256];
    __shared__ int lbh[64];
    int b = blockIdx.x, t = threadIdx.x;
    int n = bcnt[b];
    const int* w = tmp + (size_t)b * CAPR;
    cnt[t] = 0;
    if (t < 64) lbh[t] = 0;
    __syncthreads();
    for (int k = t; k < n; k += 256) atomicAdd(&cnt[w[k] >> 20], 1);
    __syncthreads();
    int node = b * 256 + t;
    int c = cnt[t];
    int pkv = 0;
    if (node < NN) {
        int m = c ? ((c + 7) >> 3) : 1;      // chunks of 8 edges
        int rl = atomicAdd(&lbh[m], 1);
        pkv = c | (rl << 9) | (m << 17);
    }
    pk[b * 256 + t] = pkv;
    __syncthreads();
    if (t < 64) gbh[b * 64 + t] = lbh[t];
}

// ---------------- global scan: per-class bucket prefixes + class tables ----------------
__global__ void k_scan(const int* __restrict__ gbh, int* __restrict__ gBinBase,
                       int* __restrict__ tabs) {
    __shared__ int tot[64];
    int t = threadIdx.x;   // 64 threads, thread t owns class t
    int run = 0;
    int b = 0;
    for (; b + 8 <= NB; b += 8) {
        int v[8];
#pragma unroll
        for (int k = 0; k < 8; ++k) v[k] = gbh[(b + k) * 64 + t];
#pragma unroll
        for (int k = 0; k < 8; ++k) { gBinBase[(b + k) * 64 + t] = run; run += v[k]; }
    }
    for (; b < NB; ++b) {
        int v = gbh[b * 64 + t];
        gBinBase[b * 64 + t] = run;
        run += v;
    }
    tot[t] = run;
    __syncthreads();
    if (t == 0) {
        int nb = 0;
        long cb = 0;
        for (int m = 63; m >= 1; --m) {
            int cN = tot[m];
            if (!cN) continue;
            tabs[200 + m] = nb;
            tabs[264 + m] = (int)cb;
            nb += cN;
            cb += (long)cN * m;
        }
    }
}

// ---------------- place: sorted work list (node|deg|m packed) + 8-padded srcList ----------------
__global__ __launch_bounds__(256) void k_place(const int* __restrict__ tmp,
                                               const int* __restrict__ bcnt,
                                               const int* __restrict__ pk,
                                               const int* __restrict__ gBinBase,
                                               const int* __restrict__ tabs,
                                               int2* __restrict__ work,
                                               int* __restrict__ srcList) {
    __shared__ int cur[256];
    int b = blockIdx.x, t = threadIdx.x;
    int n = bcnt[b];
    const int* w = tmp + (size_t)b * CAPR;
    int node = b * 256 + t;
    int pkv = pk[b * 256 + t];
    if (node < NN) {
        int c = pkv & 511;
        int rl = (pkv >> 9) & 255;
        int m = pkv >> 17;
        int rank = gBinBase[b * 64 + m] + rl;
        int sp = tabs[200 + m] + rank;
        int beg = (tabs[264 + m] + rank * m) * 8;
        unsigned y = (unsigned)node | ((unsigned)c << 17) | ((unsigned)m << 26);
        work[sp] = make_int2(beg, (int)y);
        cur[t] = beg;
        for (int k = c; k < m * 8; ++k) srcList[beg + k] = NN;   // dummy zero-row
    }
    __syncthreads();
    for (int k = t; k < n; k += 256) {
        int v = w[k];
        int pos = atomicAdd(&cur[v >> 20], 1);
        srcList[pos] = v & 0xFFFFF;
    }
}

// ---------------- gather: octet/wave, folded BN affine (exact deg), fused stats ----------------
__global__ __launch_bounds__(256) void k_gather(
    const bfu* __restrict__ Pin, bfu* __restrict__ Pout, float* __restrict__ Q,
    const int2* __restrict__ work, const int* __restrict__ srcList,
    float* __restrict__ partial, const float* __restrict__ partial2, int last) {
    __shared__ uint4 rows[4][8][64];
    __shared__ int idxb[4][2][8][64];
    __shared__ float bsum[64], bsq[64];
    __shared__ float prm[128];
    int t = threadIdx.x;
    int ws = t >> 6, l = t & 63;
    int g = l >> 3, sl = l & 7;
    if (t < 64) {
        bsum[t] = 0.f; bsq[t] = 0.f;
        float S = 0.f, SQ = 0.f;
#pragma unroll
        for (int r = 0; r < 8; ++r) {
            S += partial2[r * 128 + t];
            SQ += partial2[r * 128 + 64 + t];
        }
        float mean = S / (float)NN;
        float var = fmaxf(SQ / (float)NN - mean * mean, 0.f);
        prm[t] = rsqrtf(var + BN_EPSF);
        prm[64 + t] = mean;
    }
    __syncthreads();

    f32x4v invA, invB, mnA, mnB;
#pragma unroll
    for (int j = 0; j < 4; ++j) {
        invA[j] = prm[sl * 8 + j];
        invB[j] = prm[sl * 8 + 4 + j];
        mnA[j] = prm[64 + sl * 8 + j];
        mnB[j] = prm[64 + sl * 8 + 4 + j];
    }

    int oct = blockIdx.x * 4 + ws;
    f32x4v lsumL = {0.f, 0.f, 0.f, 0.f}, lsumH = {0.f, 0.f, 0.f, 0.f};
    f32x4v lsqL = {0.f, 0.f, 0.f, 0.f}, lsqH = {0.f, 0.f, 0.f, 0.f};

    int2 wcur = make_int2(0, 0);
    if (l < 8) wcur = work[(size_t)oct * 8 + l];
    int bg = __shfl(wcur.x, g);
    unsigned wy = (unsigned)__shfl(wcur.y, g);
    int node = wy & 0x1FFFF;
    int deg = (wy >> 17) & 0x1FF;
    int mg = (int)(wy >> 26);
    int mr = (l < 8) ? (int)(((unsigned)wcur.y) >> 26) : 0;
    mr = max(mr, __shfl_xor(mr, 1));
    mr = max(mr, __shfl_xor(mr, 2));
    mr = max(mr, __shfl_xor(mr, 4));
    int mMax = __shfl(mr, 0);
    int par = 0;
    if (mMax <= 8) {
        for (int w = 0; w < mMax; ++w)
            GLL4(srcList + bg + w * 8 + sl, &idxb[ws][0][w][0]);
    }
    WAITV0;

    for (;;) {
        int nxt = oct + TOTW;
        f32x4v aL = {0.f, 0.f, 0.f, 0.f}, aH = {0.f, 0.f, 0.f, 0.f};
        int bgN = 0, nodeN = 0, degN = 0, mgN = 0, mMaxN = 0;
        float cDp = (float)deg + 0.5f;
        uint4 selfr = *(const uint4*)(Pin + (size_t)node * 64 + sl * 8);
        if (mMax <= 8) {
            for (int w = 0; w < mMax; ++w) {
                bool lastw = (w == mMax - 1);
                int2 wnx = make_int2(0, 0);
                if (lastw && l < 8 && nxt < NOCT) wnx = work[(size_t)nxt * 8 + l];
                int sj[8];
#pragma unroll
                for (int j = 0; j < 8; ++j) sj[j] = idxb[ws][par][w][g * 8 + j];
#pragma unroll
                for (int j = 0; j < 8; ++j) {
                    int e = w * 8 + j;
                    int idv = (e < (mg << 3)) ? sj[j] : NN;
                    GLL16(Pin + (size_t)idv * 64 + sl * 8, &rows[ws][j][0]);
                }
                if (lastw) {
                    bgN = __shfl(wnx.x, g);
                    unsigned wyN = (unsigned)__shfl(wnx.y, g);
                    nodeN = wyN & 0x1FFFF;
                    degN = (wyN >> 17) & 0x1FF;
                    mgN = (int)(wyN >> 26);
                    int mrN = (l < 8) ? (int)(((unsigned)wnx.y) >> 26) : 0;
                    mrN = max(mrN, __shfl_xor(mrN, 1));
                    mrN = max(mrN, __shfl_xor(mrN, 2));
                    mrN = max(mrN, __shfl_xor(mrN, 4));
                    mMaxN = __shfl(mrN, 0);
                    if (nxt < NOCT && mMaxN <= 8) {
                        for (int w2 = 0; w2 < mMaxN; ++w2)
                            GLL4(srcList + bgN + w2 * 8 + sl, &idxb[ws][par ^ 1][w2][0]);
                    }
                }
                WAITV0;
#pragma unroll
                for (int j = 0; j < 8; ++j) acc8(rows[ws][j][l], aL, aH);
            }
        } else {
            // rare fallback: octet containing deg > 64 node
            int2 wnx = make_int2(0, 0);
            if (l < 8 && nxt < NOCT) wnx = work[(size_t)nxt * 8 + l];
            bgN = __shfl(wnx.x, g);
            unsigned wyN = (unsigned)__shfl(wnx.y, g);
            nodeN = wyN & 0x1FFFF;
            degN = (wyN >> 17) & 0x1FF;
            mgN = (int)(wyN >> 26);
            int mrN = (l < 8) ? (int)(((unsigned)wnx.y) >> 26) : 0;
            mrN = max(mrN, __shfl_xor(mrN, 1));
            mrN = max(mrN, __shfl_xor(mrN, 2));
            mrN = max(mrN, __shfl_xor(mrN, 4));
            mMaxN = __shfl(mrN, 0);
            if (nxt < NOCT && mMaxN <= 8) {
                for (int w2 = 0; w2 < mMaxN; ++w2)
                    GLL4(srcList + bgN + w2 * 8 + sl, &idxb[ws][par ^ 1][w2][0]);
            }
            WAITV0;
            for (int e = 0; e < (mg << 3); ++e) {
                int idv = srcList[bg + e];
                acc8(*(const uint4*)(Pin + (size_t)idv * 64 + sl * 8), aL, aH);
            }
        }
        // fold self + affine: a = inv*(Sum + 0.5*P[i] - (deg+0.5)*mean)
        {
            f32x4v z = {0.f, 0.f, 0.f, 0.f};
            f32x4v sLo = z, sHi = z;
            acc8(selfr, sLo, sHi);
            aL = (aL + sLo * 0.5f - mnA * cDp) * invA;
            aH = (aH + sHi * 0.5f - mnB * cDp) * invB;
        }
        if (last) {
            float* qr = Q + (size_t)node * 64 + sl * 8;
            *(f32x4v*)qr = aL;
            *(f32x4v*)(qr + 4) = aH;
        } else {
            u16x8 o;
#pragma unroll
            for (int j = 0; j < 4; ++j) { o[j] = f2bf(aL[j]); o[4 + j] = f2bf(aH[j]); }
            *(u16x8*)(Pout + (size_t)node * 64 + sl * 8) = o;
        }
        lsumL += aL; lsumH += aH;
        lsqL += aL * aL; lsqH += aH * aH;
        if (nxt >= NOCT) break;
        oct = nxt; bg = bgN; node = nodeN; deg = degN; mg = mgN; mMax = mMaxN; par ^= 1;
    }

#pragma unroll
    for (int mask = 8; mask <= 32; mask <<= 1) {
#pragma unroll
        for (int j = 0; j < 4; ++j) {
            lsumL[j] += __shfl_xor(lsumL[j], mask);
            lsumH[j] += __shfl_xor(lsumH[j], mask);
            lsqL[j] += __shfl_xor(lsqL[j], mask);
            lsqH[j] += __shfl_xor(lsqH[j], mask);
        }
    }
    if (g == 0) {
#pragma unroll
        for (int j = 0; j < 4; ++j) {
            atomicAdd(&bsum[sl * 8 + j], lsumL[j]);
            atomicAdd(&bsum[sl * 8 + 4 + j], lsumH[j]);
            atomicAdd(&bsq[sl * 8 + j], lsqL[j]);
            atomicAdd(&bsq[sl * 8 + 4 + j], lsqH[j]);
        }
    }
    __syncthreads();
    if (t < 64) {
        partial[(size_t)blockIdx.x * 128 + t] = bsum[t];
        partial[(size_t)blockIdx.x * 128 + 64 + t] = bsq[t];
    }
}

// ---------------- stage-1 reduce: 768x128 partials -> 8x128 partial2 ----------------
__global__ __launch_bounds__(256) void k_red1(const float* __restrict__ partial,
                                              float* __restrict__ partial2) {
    __shared__ float4 sacc[8][32];
    int t = threadIdx.x;
    int q = t & 31, r0 = t >> 5;          // 32 quads x 8 row-groups
    const float4* p4 = (const float4*)partial;
    int base = blockIdx.x * 96;           // 8 blocks x 96 rows = 768
    float4 a0 = make_float4(0.f, 0.f, 0.f, 0.f);
    float4 a1 = a0, a2 = a0, a3 = a0;
#pragma unroll
    for (int r = 0; r < 96; r += 32) {
        float4 v0 = p4[(base + r + r0) * 32 + q];
        float4 v1 = p4[(base + r + r0 + 8) * 32 + q];
        float4 v2 = p4[(base + r + r0 + 16) * 32 + q];
        float4 v3 = p4[(base + r + r0 + 24) * 32 + q];
        a0.x += v0.x; a0.y += v0.y; a0.z += v0.z; a0.w += v0.w;
        a1.x += v1.x; a1.y += v1.y; a1.z += v1.z; a1.w += v1.w;
        a2.x += v2.x; a2.y += v2.y; a2.z += v2.z; a2.w += v2.w;
        a3.x += v3.x; a3.y += v3.y; a3.z += v3.z; a3.w += v3.w;
    }
    a0.x += a1.x + a2.x + a3.x;
    a0.y += a1.y + a2.y + a3.y;
    a0.z += a1.z + a2.z + a3.z;
    a0.w += a1.w + a2.w + a3.w;
    sacc[r0][q] = a0;
    __syncthreads();
    if (t < 32) {
        float4 s = sacc[0][t];
#pragma unroll
        for (int r = 1; r < 8; ++r) {
            float4 v = sacc[r][t];
            s.x += v.x; s.y += v.y; s.z += v.z; s.w += v.w;
        }
        ((float4*)partial2)[blockIdx.x * 32 + t] = s;
    }
}

// ---------------- final: normalize agg(Q) -> fp32 out (stats from partial2) ----------------
__global__ __launch_bounds__(256) void k_final(const float* __restrict__ Q,
                                               const float* __restrict__ partial2,
                                               float* __restrict__ out) {
    __shared__ float prm[128];
    int t = threadIdx.x;
    if (t < 64) {
        float S = 0.f, SQ = 0.f;
#pragma unroll
        for (int r = 0; r < 8; ++r) {
            S += partial2[r * 128 + t];
            SQ += partial2[r * 128 + 64 + t];
        }
        float mean = S / (float)NN;
        float var = fmaxf(SQ / (float)NN - mean * mean, 0.f);
        prm[t] = rsqrtf(var + BN_EPSF);
        prm[64 + t] = mean;
    }
    __syncthreads();
    int idx = blockIdx.x * 256 + t;
    if (idx >= NN * 16) return;
    int i = idx >> 4, fq = idx & 15;
    f32x4v a = *(const f32x4v*)(Q + (size_t)i * 64 + fq * 4);
    f32x4v o;
    o.x = (a.x - prm[64 + fq * 4 + 0]) * prm[fq * 4 + 0];
    o.y = (a.y - prm[64 + fq * 4 + 1]) * prm[fq * 4 + 1];
    o.z = (a.z - prm[64 + fq * 4 + 2]) * prm[fq * 4 + 2];
    o.w = (a.w - prm[64 + fq * 4 + 3]) * prm[fq * 4 + 3];
    *(f32x4v*)(out + (size_t)i * 64 + fq * 4) = o;
}

extern "C" void kernel_launch(void* const* d_in, const int* in_sizes, int n_in,
                              void* d_out, int out_size, void* d_ws, size_t ws_size,
                              hipStream_t stream) {
    const int* x = (const int*)d_in[0];
    const int* ei = (const int*)d_in[1];
    const float* table = (const float*)d_in[2];
    const int* src = ei;
    const int* dst = ei + NE;
    float* out = (float*)d_out;

    // workspace carve-up (~70 MB); keep 16B alignment for float4 users
    bfu* PA = (bfu*)d_ws;                                  // (NN+1)*64 bf16
    bfu* PB = PA + (size_t)(NN + 1) * 64;                  // (NN+1)*64 bf16
    float* Q = (float*)(PB + (size_t)(NN + 1) * 64);       // NN*64 f32
    int* srcList = (int*)(Q + (size_t)NN * 64);            // SRCCAP
    int* tmp = srcList + SRCCAP;                           // NB*CAPR
    int2* work = (int2*)(tmp + (size_t)NB * CAPR);         // NN int2
    int* pk = (int*)(work + NN);                           // NB*256
    int* gBinBase = pk + NB * 256;                         // NB*64
    int* gbh = gBinBase + NB * 64;                         // NB*64
    float* partial = (float*)(gbh + NB * 64);              // LBLK*128 (16B aligned)
    float* partial2 = partial + (size_t)LBLK * 128;        // 8*128
    int* bcnt = (int*)(partial2 + 8 * 128);                // NB
    int* tabs = bcnt + NB + 9;                             // 512 (aligned not needed)

    k_embed<<<((NN + 1) * 16 + 255) / 256, 256, 0, stream>>>(x, table, PA, PB, bcnt, partial2);

    const int NPB = (NE + 2047) / 2048;  // 782
    k_part<<<NPB, 256, 0, stream>>>(src, dst, bcnt, tmp);
    k_cnt<<<NB, 256, 0, stream>>>(tmp, bcnt, pk, gbh);
    k_scan<<<1, 64, 0, stream>>>(gbh, gBinBase, tabs);
    k_place<<<NB, 256, 0, stream>>>(tmp, bcnt, pk, gBinBase, tabs, work, srcList);

    // 5 layers: gather (stats->partial) -> red1 (partial->partial2)
    bfu* Pin = PA;
    bfu* Pout = PB;
    for (int L = 0; L < NLAYERS; ++L) {
        int last = (L == NLAYERS - 1);
        k_gather<<<LBLK, 256, 0, stream>>>(Pin, Pout, Q, work, srcList, partial, partial2, last);
        k_red1<<<8, 256, 0, stream>>>(partial, partial2);
        bfu* tswap = Pin; Pin = Pout; Pout = tswap;
    }
    k_final<<<(NN * 16 + 255) / 256, 256, 0, stream>>>(Q, partial2, out);
}